// Round 5
// baseline (821.623 us; speedup 1.0000x reference)
//
#include <hip/hip_runtime.h>
#include <cstdint>
#include <cstddef>

// Problem constants
#define BB 4
#define SS 4096
#define DD 1024
#define HH 16
#define MM (BB*SS)          // 16384 rows

typedef __bf16 bf16x8 __attribute__((ext_vector_type(8)));
typedef float  f32x4  __attribute__((ext_vector_type(4)));

__device__ __forceinline__ float b2f(unsigned short h){
    union { unsigned int u; float f; } c; c.u = ((unsigned int)h) << 16; return c.f;
}
__device__ __forceinline__ float b2f_u(unsigned int u16){
    union { unsigned int u; float f; } c; c.u = u16 << 16; return c.f;
}
__device__ __forceinline__ unsigned short f2b(float f){
    union { float f; unsigned int u; } c; c.f = f;
    unsigned int u = c.u + 0x7FFFu + ((c.u >> 16) & 1u);   // RNE
    return (unsigned short)(u >> 16);
}

// ---------------------------------------------------------------- fused transpose+cvt for all 5 weights
__global__ __launch_bounds__(256) void transpose_cvt_all(
        const float* __restrict__ wqkv, const float* __restrict__ wout,
        const float* __restrict__ w1,   const float* __restrict__ w2,
        const float* __restrict__ w3,
        unsigned short* __restrict__ dqkv, unsigned short* __restrict__ dout,
        unsigned short* __restrict__ d1,   unsigned short* __restrict__ d2,
        unsigned short* __restrict__ d3)
{
    int id = blockIdx.x;
    const float* src; unsigned short* dst; int K, N, bx, by;
    if (id < 3072)       { src=wqkv; dst=dqkv; K=1024; N=3072; int r=id;        bx=r%96; by=r/96; }
    else if (id < 4096)  { src=wout; dst=dout; K=1024; N=1024; int r=id-3072;   bx=r%32; by=r/32; }
    else if (id < 6144)  { src=w1;   dst=d1;   K=1024; N=2048; int r=id-4096;   bx=r%64; by=r/64; }
    else if (id < 10240) { src=w2;   dst=d2;   K=2048; N=2048; int r=id-6144;   bx=r%64; by=r/64; }
    else                 { src=w3;   dst=d3;   K=2048; N=1024; int r=id-10240;  bx=r%32; by=r/32; }

    __shared__ float tile[32][33];
    int kb = by*32, nb = bx*32;
    int tx = threadIdx.x & 31, ty = threadIdx.x >> 5;
    for(int i=0;i<32;i+=8) tile[ty+i][tx] = src[(size_t)(kb+ty+i)*N + nb+tx];
    __syncthreads();
    for(int i=0;i<32;i+=8) dst[(size_t)(nb+ty+i)*K + kb+tx] = f2b(tile[tx][ty+i]);
}

// ---------------------------------------------------------------- layernorm (+ optional sinusoidal PE)
template<int INBF>
__global__ __launch_bounds__(256) void ln_kernel(const void* __restrict__ xin,
                                                 const float* __restrict__ g,
                                                 const float* __restrict__ bta,
                                                 unsigned short* __restrict__ out,
                                                 int add_pe){
    int row = blockIdx.x;
    int t = threadIdx.x;
    float4 v;
    if (INBF == 0) {
        v = ((const float4*)((const float*)xin + (size_t)row*DD))[t];
    } else {
        ushort4 u = ((const ushort4*)((const unsigned short*)xin + (size_t)row*DD))[t];
        v.x = b2f(u.x); v.y = b2f(u.y); v.z = b2f(u.z); v.w = b2f(u.w);
    }
    float s = v.x+v.y+v.z+v.w;
    float q = v.x*v.x+v.y*v.y+v.z*v.z+v.w*v.w;
    for(int off=32; off>0; off>>=1){ s += __shfl_xor(s, off); q += __shfl_xor(q, off); }
    __shared__ float red[8];
    int wv = t>>6, ln = t&63;
    if(ln==0){ red[wv] = s; red[4+wv] = q; }
    __syncthreads();
    s = red[0]+red[1]+red[2]+red[3];
    q = red[4]+red[5]+red[6]+red[7];
    float mu = s * (1.0f/1024.0f);
    float var = q * (1.0f/1024.0f) - mu*mu;
    float rs = rsqrtf(var + 1e-6f);
    int d0 = t*4;
    float4 gg = ((const float4*)g)[t];
    float4 bb = ((const float4*)bta)[t];
    float o0 = (v.x-mu)*rs*gg.x + bb.x;
    float o1 = (v.y-mu)*rs*gg.y + bb.y;
    float o2 = (v.z-mu)*rs*gg.z + bb.z;
    float o3 = (v.w-mu)*rs*gg.w + bb.w;
    if(add_pe){
        int sidx = row & (SS-1);
        const float cfac = -0.008994473019508968f;   // -ln(10000)/1024
        float a0 = (float)sidx * expf(cfac * (float)(d0));
        float a1 = (float)sidx * expf(cfac * (float)(d0 + 2));
        o0 += sinf(a0); o1 += cosf(a0);
        o2 += sinf(a1); o3 += cosf(a1);
    }
    ushort4 o;
    o.x = f2b(o0); o.y = f2b(o1); o.z = f2b(o2); o.w = f2b(o3);
    *(ushort4*)(out + (size_t)row*DD + d0) = o;
}

// ---------------------------------------------------------------- 256x256 8-phase bf16 MFMA GEMM (v4: pinned reads)
// Identical to the round-2 template-faithful schedule, plus ONE change: sched_barrier(0)
// immediately after each phase's ds_read group.  s_barrier carries no memory-motion
// semantics in LLVM, so without the pin the compiler sinks the ds_reads across the
// barrier to just before the MFMA, serializing read-burst + MFMA (measured 36% MfmaUtil).
// Pinning keeps the reads in the barrier-wait window (the template's intended overlap).

#define BARX __builtin_amdgcn_s_barrier()
#define PIN  __builtin_amdgcn_sched_barrier(0)
#define LGK0 { asm volatile("s_waitcnt lgkmcnt(0)" ::: "memory"); __builtin_amdgcn_sched_barrier(0); }
#define LGK8 asm volatile("s_waitcnt lgkmcnt(8)" ::: "memory")
#define VM6  asm volatile("s_waitcnt vmcnt(6)" ::: "memory")
#define PRIO1 __builtin_amdgcn_s_setprio(1)
#define PRIO0 __builtin_amdgcn_s_setprio(0)

#define LDA(D, QR) { \
    const char* _pa = sA + (((D)*2+(QR))<<14) + rbaseA; \
    _Pragma("unroll") \
    for (int mi = 0; mi < 4; mi++) { \
        ra[mi][0] = *(const bf16x8*)(_pa + (mi<<11) + kb0); \
        ra[mi][1] = *(const bf16x8*)(_pa + (mi<<11) + kb1); \
    } }

#define LDB(RB, D, QC) { \
    const char* _pb = sB + (((D)*2+(QC))<<14) + rbaseB; \
    _Pragma("unroll") \
    for (int nj = 0; nj < 2; nj++) { \
        RB[nj][0] = *(const bf16x8*)(_pb + (nj<<11) + kb0); \
        RB[nj][1] = *(const bf16x8*)(_pb + (nj<<11) + kb1); \
    } }

#define MMAC(RB, QR, QC) { \
    _Pragma("unroll") \
    for (int mi = 0; mi < 4; mi++) \
    _Pragma("unroll") \
    for (int nj = 0; nj < 2; nj++) \
    _Pragma("unroll") \
    for (int kk = 0; kk < 2; kk++) \
        acc[(QR)*4+mi][(QC)*2+nj] = __builtin_amdgcn_mfma_f32_16x16x32_bf16( \
            ra[mi][kk], RB[nj][kk], acc[(QR)*4+mi][(QC)*2+nj], 0, 0, 0); }

#define STAGEA(D, H, KS) { \
    __builtin_amdgcn_global_load_lds((const __attribute__((address_space(1))) void*)(pA[H][0] + (KS)), \
        (__attribute__((address_space(3))) void*)(sA + (((D)*2+(H))<<14) + wbase), 16, 0, 0); \
    __builtin_amdgcn_global_load_lds((const __attribute__((address_space(1))) void*)(pA[H][1] + (KS)), \
        (__attribute__((address_space(3))) void*)(sA + (((D)*2+(H))<<14) + wbase + 8192), 16, 0, 0); }

#define STAGEB(D, Q, KS) { \
    __builtin_amdgcn_global_load_lds((const __attribute__((address_space(1))) void*)(pB[Q][0] + (KS)), \
        (__attribute__((address_space(3))) void*)(sB + (((D)*2+(Q))<<14) + wbase), 16, 0, 0); \
    __builtin_amdgcn_global_load_lds((const __attribute__((address_space(1))) void*)(pB[Q][1] + (KS)), \
        (__attribute__((address_space(3))) void*)(sB + (((D)*2+(Q))<<14) + wbase + 8192), 16, 0, 0); }

template<int EPI>
__global__ __launch_bounds__(512, 2) void gemm256(
        const unsigned short* __restrict__ A,
        const unsigned short* __restrict__ Bt,
        void* __restrict__ Cout,
        const float* __restrict__ bias,
        const void* __restrict__ resid,
        int M, int N, int K)
{
    __shared__ __align__(16) unsigned short lAbuf[2*2*128*64];   // 64 KiB
    __shared__ __align__(16) unsigned short lBbuf[2*2*128*64];   // 64 KiB
    char* sA = (char*)lAbuf;
    char* sB = (char*)lBbuf;

    const int tid  = threadIdx.x;
    const int lane = tid & 63;
    const int wave = tid >> 6;        // 0..7
    const int quad = lane >> 4;
    const int l16  = lane & 15;
    const int wr = wave >> 2;         // 0..1 (M)
    const int wc = wave & 3;          // 0..3 (N)

    // XCD-aware bijective tile swizzle (all grids here have nwg % 8 == 0)
    int gn  = gridDim.x;
    int lin = blockIdx.y * gn + blockIdx.x;
    int xcd = lin & 7;
    int j   = lin >> 3;
    int mt  = xcd + 8*(j/gn);
    int nt  = j - (j/gn)*gn;
    const int m0 = mt * 256;
    const int n0 = nt * 256;

    // per-thread stage source pointers (inverse-swizzled global, linear LDS dest)
    const unsigned short* pA[2][2];
    const unsigned short* pB[2][2];
    #pragma unroll
    for (int h = 0; h < 2; h++) {
        #pragma unroll
        for (int jj = 0; jj < 2; jj++) {
            int c  = tid + 512*jj;
            int lr = c >> 3;
            int kc = ((c & 7) ^ (lr & 7)) << 3;   // elements
            int ga = m0 + ((lr>>6)<<7) + h*64 + (lr & 63);
            int gb = n0 + ((lr>>5)<<6) + h*32 + (lr & 31);
            pA[h][jj] = A  + (size_t)ga * K + kc;
            pB[h][jj] = Bt + (size_t)gb * K + kc;
        }
    }
    const int wbase  = wave << 10;                    // lanes add lane*16
    const int rbaseA = (wr*64 + l16) * 128;
    const int rbaseB = (wc*32 + l16) * 128;
    const int kb0 = (quad*16)      ^ ((l16 & 7) << 4);
    const int kb1 = (64 + quad*16) ^ ((l16 & 7) << 4);

    f32x4 acc[8][4] = {};          // [qr*4+mi][qc*2+nj]
    bf16x8 ra[4][2], rb0[2][2], rb1[2][2];

    // ---- prologue: tile0 (d0 all 4 halves) + tile1 (d1: Aqr0,Bqc0,Bqc1)
    STAGEA(0,0, 0); STAGEB(0,0, 0); STAGEB(0,1, 0); STAGEA(0,1, 0);
    STAGEA(1,0, 64); STAGEB(1,0, 64); STAGEB(1,1, 64);
    VM6;                            // tile0's 8 loads landed; 3 half-tiles in flight
    BARX;

    const int NIT = K >> 7;         // 2 K-tiles per iteration
    for (int it = 0; it < NIT; it++) {
        int ka  = it << 7;
        int kb_ = ka + 64;                       // tile 2i+1 (last half staged at p1)
        int kc2 = ka + 128; if (kc2 >= K) kc2 = 0;  // tile 2i+2 -> d0 (wrap: dummy, safe)
        int kc3 = ka + 192; if (kc3 >= K) kc3 = 0;  // tile 2i+3 -> d1

        // p1: Q1(d0)=(A0,B0); stage d1.Aqr1
        LDA(0,0); LDB(rb0, 0,0);
        PIN;                                    // pin reads before stage+barrier
        STAGEA(1,1, kb_);
        LGK8;
        BARX; LGK0; PRIO1; MMAC(rb0, 0,0); PRIO0; BARX;
        // p2: Q2(d0)=(A0,B1); stage d0'.Aqr0
        LDB(rb1, 0,1);
        PIN;
        STAGEA(0,0, kc2);
        BARX; LGK0; PRIO1; MMAC(rb1, 0,1); PRIO0; BARX;
        // p3: Q3(d0)=(A1,B1); stage d0'.Bqc0
        LDA(0,1);
        PIN;
        STAGEB(0,0, kc2);
        BARX; LGK0; PRIO1; MMAC(rb1, 1,1); PRIO0; BARX;
        // p4: Q4(d0)=(A1,B0) (rb0 held in regs); stage d0'.Bqc1; counted vmcnt
        STAGEB(0,1, kc2);
        VM6;
        BARX; LGK0; PRIO1; MMAC(rb0, 1,0); PRIO0; BARX;
        // p5: Q1(d1)=(A0,B0); stage d0'.Aqr1
        LDA(1,0); LDB(rb0, 1,0);
        PIN;
        STAGEA(0,1, kc2);
        LGK8;
        BARX; LGK0; PRIO1; MMAC(rb0, 0,0); PRIO0; BARX;
        // p6: Q2(d1)=(A0,B1); stage d1'.Aqr0
        LDB(rb1, 1,1);
        PIN;
        STAGEA(1,0, kc3);
        BARX; LGK0; PRIO1; MMAC(rb1, 0,1); PRIO0; BARX;
        // p7: Q3(d1)=(A1,B1); stage d1'.Bqc0
        LDA(1,1);
        PIN;
        STAGEB(1,0, kc3);
        BARX; LGK0; PRIO1; MMAC(rb1, 1,1); PRIO0; BARX;
        // p8: Q4(d1)=(A1,B0); stage d1'.Bqc1; counted vmcnt
        STAGEB(1,1, kc3);
        VM6;
        BARX; LGK0; PRIO1; MMAC(rb0, 1,0); PRIO0; BARX;
    }
    asm volatile("s_waitcnt vmcnt(0)" ::: "memory");   // drain before exit

    // ---- epilogue
    #pragma unroll
    for (int qm = 0; qm < 8; qm++) {
        int grow0 = m0 + wr*128 + (qm>>2)*64 + (qm&3)*16 + quad*4;
        #pragma unroll
        for (int r = 0; r < 4; r++) {
            int grow = grow0 + r;
            #pragma unroll
            for (int ni = 0; ni < 4; ni++) {
                int gcol = n0 + wc*64 + ni*16 + l16;
                float v = acc[qm][ni][r];
                size_t idx = (size_t)grow * N + gcol;
                if (EPI == 0) {
                    ((unsigned short*)Cout)[idx] = f2b(v);
                } else if (EPI == 1) {
                    v += bias[gcol];
                    v = 0.5f * v * (1.0f + erff(v * 0.70710678118654752f));
                    ((unsigned short*)Cout)[idx] = f2b(v);
                } else if (EPI == 2) {
                    v += bias[gcol] + ((const float*)resid)[idx];
                    ((unsigned short*)Cout)[idx] = f2b(v);
                } else {
                    v += bias[gcol] + b2f(((const unsigned short*)resid)[idx]);
                    ((float*)Cout)[idx] = v;
                }
            }
        }
    }
}

// ---------------------------------------------------------------- context partials (k-softmax folded)
__global__ __launch_bounds__(256) void ctx_partial(const unsigned short* __restrict__ qkv,
                                                   float* __restrict__ EP,
                                                   float* __restrict__ CS){
    int sc = blockIdx.x, h = blockIdx.y, b = blockIdx.z;
    int t = threadIdx.x;
    __shared__ __align__(16) float kl[64][64];   // exp(k)
    __shared__ __align__(16) float vl[64][64];
    __shared__ float csred[4][64];
    float acc[4][4] = {};
    float cspart = 0.0f;
    int e4 = (t & 15) * 4, d4 = (t >> 4) * 4;
    int dcol = t & 63, schunk = t >> 6;
    for(int s0 = 0; s0 < 256; s0 += 64){
        __syncthreads();
        #pragma unroll
        for(int j=0;j<2;j++){
            int lin = t + 256*j;
            int row = lin >> 3;
            int c8  = (lin & 7) * 8;
            size_t gr = (size_t)(b*SS + sc*256 + s0 + row);
            uint4 kv = *(const uint4*)(qkv + gr*3072 + DD + h*64 + c8);
            float4 ka, kb2;
            ka.x = expf(b2f_u(kv.x & 0xFFFFu)); ka.y = expf(b2f_u(kv.x >> 16));
            ka.z = expf(b2f_u(kv.y & 0xFFFFu)); ka.w = expf(b2f_u(kv.y >> 16));
            kb2.x = expf(b2f_u(kv.z & 0xFFFFu)); kb2.y = expf(b2f_u(kv.z >> 16));
            kb2.z = expf(b2f_u(kv.w & 0xFFFFu)); kb2.w = expf(b2f_u(kv.w >> 16));
            *(float4*)&kl[row][c8]   = ka;
            *(float4*)&kl[row][c8+4] = kb2;
            uint4 vv = *(const uint4*)(qkv + gr*3072 + 2*DD + h*64 + c8);
            float4 va, vb;
            va.x = b2f_u(vv.x & 0xFFFFu); va.y = b2f_u(vv.x >> 16);
            va.z = b2f_u(vv.y & 0xFFFFu); va.w = b2f_u(vv.y >> 16);
            vb.x = b2f_u(vv.z & 0xFFFFu); vb.y = b2f_u(vv.z >> 16);
            vb.z = b2f_u(vv.w & 0xFFFFu); vb.w = b2f_u(vv.w >> 16);
            *(float4*)&vl[row][c8]   = va;
            *(float4*)&vl[row][c8+4] = vb;
        }
        __syncthreads();
        #pragma unroll
        for(int i=0;i<16;i++) cspart += kl[schunk*16+i][dcol];
        for(int s=0;s<64;s++){
            float4 k4 = *(const float4*)&kl[s][d4];
            float4 v4 = *(const float4*)&vl[s][e4];
            acc[0][0] += k4.x*v4.x; acc[0][1] += k4.x*v4.y; acc[0][2] += k4.x*v4.z; acc[0][3] += k4.x*v4.w;
            acc[1][0] += k4.y*v4.x; acc[1][1] += k4.y*v4.y; acc[1][2] += k4.y*v4.z; acc[1][3] += k4.y*v4.w;
            acc[2][0] += k4.z*v4.x; acc[2][1] += k4.z*v4.y; acc[2][2] += k4.z*v4.z; acc[2][3] += k4.z*v4.w;
            acc[3][0] += k4.w*v4.x; acc[3][1] += k4.w*v4.y; acc[3][2] += k4.w*v4.z; acc[3][3] += k4.w*v4.w;
        }
    }
    int slot = (b*HH + h)*16 + sc;
    float* ep = EP + (size_t)slot*4096;
    #pragma unroll
    for(int i=0;i<4;i++)
        *(float4*)&ep[(d4+i)*64 + e4] = *(float4*)&acc[i][0];
    csred[schunk][dcol] = cspart;
    __syncthreads();
    if(t < 64) CS[slot*64 + t] = csred[0][t]+csred[1][t]+csred[2][t]+csred[3][t];
}

// ---------------------------------------------------------------- reduce 16 slots, divide by colsum
__global__ __launch_bounds__(256) void ctx_reduce(const float* __restrict__ EP,
                                                  const float* __restrict__ CS,
                                                  float* __restrict__ CTXF){
    int bh = blockIdx.x;
    int t = threadIdx.x;
    int d = t >> 2, e0 = (t & 3) * 16;
    float cs = 0.0f;
    #pragma unroll
    for(int sl=0; sl<16; sl++) cs += CS[(bh*16+sl)*64 + d];
    float inv = 1.0f/cs;
    #pragma unroll
    for(int i=0;i<16;i++){
        float s = 0.0f;
        #pragma unroll
        for(int sl=0; sl<16; sl++) s += EP[(size_t)(bh*16+sl)*4096 + d*64 + e0 + i];
        CTXF[(size_t)bh*4096 + d*64 + e0 + i] = s * inv;
    }
}

// ---------------------------------------------------------------- attn = softmax(q)/8 @ ctx  (q-softmax fused)
__global__ __launch_bounds__(256) void attn_heads(const unsigned short* __restrict__ qkv,
                                                  const float* __restrict__ CTXF,
                                                  unsigned short* __restrict__ abuf){
    int rg = blockIdx.x, h = blockIdx.y;
    int b = rg >> 6;
    int t = threadIdx.x;
    __shared__ __align__(16) float cl[64][64];
    __shared__ __align__(16) float qlT[64*68];    // [d][r], row stride 68 floats
    const float* cb = CTXF + (size_t)(b*HH + h)*4096;
    for(int j=0;j<4;j++){
        int lin = t + 256*j;
        ((float4*)cl)[lin] = ((const float4*)cb)[lin];
    }
    {
        int r = t >> 2, seg = (t & 3) * 16;
        const unsigned short* qp = qkv + (size_t)(rg*64 + r)*3072 + h*64 + seg;
        float vals[16];
        float m = -1e30f;
        #pragma unroll
        for(int u=0; u<4; u++){
            ushort4 qv = *(const ushort4*)(qp + u*4);
            vals[u*4+0]=b2f(qv.x); vals[u*4+1]=b2f(qv.y); vals[u*4+2]=b2f(qv.z); vals[u*4+3]=b2f(qv.w);
        }
        #pragma unroll
        for(int i=0;i<16;i++) m = fmaxf(m, vals[i]);
        m = fmaxf(m, __shfl_xor(m, 1));
        m = fmaxf(m, __shfl_xor(m, 2));
        float ssum = 0.0f;
        #pragma unroll
        for(int i=0;i<16;i++){ vals[i] = expf(vals[i]-m); ssum += vals[i]; }
        ssum += __shfl_xor(ssum, 1);
        ssum += __shfl_xor(ssum, 2);
        float scl = 0.125f/ssum;
        #pragma unroll
        for(int i=0;i<16;i++) qlT[(seg+i)*68 + r] = vals[i]*scl;
    }
    __syncthreads();
    int e4 = (t & 15) * 4, r4 = (t >> 4) * 4;
    float acc[4][4] = {};
    for(int d=0; d<64; d++){
        float4 q4 = *(const float4*)&qlT[d*68 + r4];
        float4 c4 = *(const float4*)&cl[d][e4];
        acc[0][0] += q4.x*c4.x; acc[0][1] += q4.x*c4.y; acc[0][2] += q4.x*c4.z; acc[0][3] += q4.x*c4.w;
        acc[1][0] += q4.y*c4.x; acc[1][1] += q4.y*c4.y; acc[1][2] += q4.y*c4.z; acc[1][3] += q4.y*c4.w;
        acc[2][0] += q4.z*c4.x; acc[2][1] += q4.z*c4.y; acc[2][2] += q4.z*c4.z; acc[2][3] += q4.z*c4.w;
        acc[3][0] += q4.w*c4.x; acc[3][1] += q4.w*c4.y; acc[3][2] += q4.w*c4.z; acc[3][3] += q4.w*c4.w;
    }
    #pragma unroll
    for(int i=0;i<4;i++){
        ushort4 o;
        o.x = f2b(acc[i][0]); o.y = f2b(acc[i][1]); o.z = f2b(acc[i][2]); o.w = f2b(acc[i][3]);
        *(ushort4*)(abuf + (size_t)(rg*64 + r4 + i)*DD + h*64 + e4) = o;
    }
}

// ---------------------------------------------------------------- launch
extern "C" void kernel_launch(void* const* d_in, const int* in_sizes, int n_in,
                              void* d_out, int out_size, void* d_ws, size_t ws_size,
                              hipStream_t stream)
{
    const float* x     = (const float*)d_in[0];
    const float* ln1_g = (const float*)d_in[1];
    const float* ln1_b = (const float*)d_in[2];
    const float* w_qkv = (const float*)d_in[3];
    const float* w_out = (const float*)d_in[4];
    const float* b_out = (const float*)d_in[5];
    const float* ln2_g = (const float*)d_in[6];
    const float* ln2_b = (const float*)d_in[7];
    const float* w1    = (const float*)d_in[8];
    const float* b1    = (const float*)d_in[9];
    const float* w2    = (const float*)d_in[10];
    const float* b2    = (const float*)d_in[11];
    const float* w3    = (const float*)d_in[12];
    const float* b3    = (const float*)d_in[13];

    // ---- workspace layout (aliases temporally disjoint) ----
    char* ws = (char*)d_ws;
    unsigned short* wqkvT = (unsigned short*)(ws + 0);            // 6291456 B
    unsigned short* woutT = (unsigned short*)(ws + 6291456);      // 2097152 B
    unsigned short* w1T   = (unsigned short*)(ws + 8388608);      // 4194304 B
    unsigned short* w2T   = (unsigned short*)(ws + 12582912);     // 8388608 B
    unsigned short* w3T   = (unsigned short*)(ws + 20971520);     // 4194304 B
    unsigned short* Hbuf  = (unsigned short*)(ws + 25165824);     // 32 MB (ln1 out; later Abuf/H2)
    unsigned short* QKV   = (unsigned short*)(ws + 58720256);     // 96 MB (dead after attn_heads)
    float*          EP    = (float*)(ws + 159383552);             // 16 MB (attn phase)
    float*          CS    = (float*)(ws + 176160768);             // 256 KB
    float*          CTXF  = (float*)(ws + 176422912);             // 1 MB
    // phase 2 aliases:
    unsigned short* Abuf  = Hbuf;
    unsigned short* X2    = (unsigned short*)(ws + 58720256);     // x+attn bf16 [M,1024]
    unsigned short* H2    = Hbuf;
    unsigned short* Y1    = (unsigned short*)d_out;               // [M,2048] bf16 = out buffer
    unsigned short* Y2    = (unsigned short*)(ws + 125829120);    // 64 MB

    transpose_cvt_all<<<12288, 256, 0, stream>>>(w_qkv, w_out, w1, w2, w3,
                                                 wqkvT, woutT, w1T, w2T, w3T);

    ln_kernel<0><<<MM, 256, 0, stream>>>(x, ln1_g, ln1_b, Hbuf, 1);

    gemm256<0><<<dim3(3072/256, MM/256), 512, 0, stream>>>(Hbuf, wqkvT, QKV, nullptr, nullptr, MM, 3072, 1024);

    ctx_partial<<<dim3(16, HH, BB), 256, 0, stream>>>(QKV, EP, CS);
    ctx_reduce<<<BB*HH, 256, 0, stream>>>(EP, CS, CTXF);
    attn_heads<<<dim3(256, HH), 256, 0, stream>>>(QKV, CTXF, Abuf);

    gemm256<2><<<dim3(1024/256, MM/256), 512, 0, stream>>>(Abuf, woutT, X2, b_out, x, MM, 1024, 1024);

    ln_kernel<1><<<MM, 256, 0, stream>>>(X2, ln2_g, ln2_b, H2, 0);

    gemm256<1><<<dim3(2048/256, MM/256), 512, 0, stream>>>(H2, w1T, Y1, b1, nullptr, MM, 2048, 1024);
    gemm256<1><<<dim3(2048/256, MM/256), 512, 0, stream>>>(Y1, w2T, Y2, b2, nullptr, MM, 2048, 2048);
    gemm256<3><<<dim3(1024/256, MM/256), 512, 0, stream>>>(Y2, w3T, d_out, b3, X2, MM, 1024, 2048);
}

// Round 6
// 748.753 us; speedup vs baseline: 1.0973x; 1.0973x over previous
//
#include <hip/hip_runtime.h>
#include <cstdint>
#include <cstddef>

// Problem constants
#define BB 4
#define SS 4096
#define DD 1024
#define HH 16
#define MM (BB*SS)          // 16384 rows

typedef __bf16 bf16x8 __attribute__((ext_vector_type(8)));
typedef float  f32x4  __attribute__((ext_vector_type(4)));

__device__ __forceinline__ float b2f(unsigned short h){
    union { unsigned int u; float f; } c; c.u = ((unsigned int)h) << 16; return c.f;
}
__device__ __forceinline__ float b2f_u(unsigned int u16){
    union { unsigned int u; float f; } c; c.u = u16 << 16; return c.f;
}
__device__ __forceinline__ unsigned short f2b(float f){
    union { float f; unsigned int u; } c; c.f = f;
    unsigned int u = c.u + 0x7FFFu + ((c.u >> 16) & 1u);   // RNE
    return (unsigned short)(u >> 16);
}

// ---------------------------------------------------------------- fused transpose+cvt for all 5 weights
__global__ __launch_bounds__(256) void transpose_cvt_all(
        const float* __restrict__ wqkv, const float* __restrict__ wout,
        const float* __restrict__ w1,   const float* __restrict__ w2,
        const float* __restrict__ w3,
        unsigned short* __restrict__ dqkv, unsigned short* __restrict__ dout,
        unsigned short* __restrict__ d1,   unsigned short* __restrict__ d2,
        unsigned short* __restrict__ d3)
{
    int id = blockIdx.x;
    const float* src; unsigned short* dst; int K, N, bx, by;
    if (id < 3072)       { src=wqkv; dst=dqkv; K=1024; N=3072; int r=id;        bx=r%96; by=r/96; }
    else if (id < 4096)  { src=wout; dst=dout; K=1024; N=1024; int r=id-3072;   bx=r%32; by=r/32; }
    else if (id < 6144)  { src=w1;   dst=d1;   K=1024; N=2048; int r=id-4096;   bx=r%64; by=r/64; }
    else if (id < 10240) { src=w2;   dst=d2;   K=2048; N=2048; int r=id-6144;   bx=r%64; by=r/64; }
    else                 { src=w3;   dst=d3;   K=2048; N=1024; int r=id-10240;  bx=r%32; by=r/32; }

    __shared__ float tile[32][33];
    int kb = by*32, nb = bx*32;
    int tx = threadIdx.x & 31, ty = threadIdx.x >> 5;
    for(int i=0;i<32;i+=8) tile[ty+i][tx] = src[(size_t)(kb+ty+i)*N + nb+tx];
    __syncthreads();
    for(int i=0;i<32;i+=8) dst[(size_t)(nb+ty+i)*K + kb+tx] = f2b(tile[tx][ty+i]);
}

// ---------------------------------------------------------------- layernorm (+ optional sinusoidal PE)
template<int INBF>
__global__ __launch_bounds__(256) void ln_kernel(const void* __restrict__ xin,
                                                 const float* __restrict__ g,
                                                 const float* __restrict__ bta,
                                                 unsigned short* __restrict__ out,
                                                 int add_pe){
    int row = blockIdx.x;
    int t = threadIdx.x;
    float4 v;
    if (INBF == 0) {
        v = ((const float4*)((const float*)xin + (size_t)row*DD))[t];
    } else {
        ushort4 u = ((const ushort4*)((const unsigned short*)xin + (size_t)row*DD))[t];
        v.x = b2f(u.x); v.y = b2f(u.y); v.z = b2f(u.z); v.w = b2f(u.w);
    }
    float s = v.x+v.y+v.z+v.w;
    float q = v.x*v.x+v.y*v.y+v.z*v.z+v.w*v.w;
    for(int off=32; off>0; off>>=1){ s += __shfl_xor(s, off); q += __shfl_xor(q, off); }
    __shared__ float red[8];
    int wv = t>>6, ln = t&63;
    if(ln==0){ red[wv] = s; red[4+wv] = q; }
    __syncthreads();
    s = red[0]+red[1]+red[2]+red[3];
    q = red[4]+red[5]+red[6]+red[7];
    float mu = s * (1.0f/1024.0f);
    float var = q * (1.0f/1024.0f) - mu*mu;
    float rs = rsqrtf(var + 1e-6f);
    int d0 = t*4;
    float4 gg = ((const float4*)g)[t];
    float4 bb = ((const float4*)bta)[t];
    float o0 = (v.x-mu)*rs*gg.x + bb.x;
    float o1 = (v.y-mu)*rs*gg.y + bb.y;
    float o2 = (v.z-mu)*rs*gg.z + bb.z;
    float o3 = (v.w-mu)*rs*gg.w + bb.w;
    if(add_pe){
        int sidx = row & (SS-1);
        const float cfac = -0.008994473019508968f;   // -ln(10000)/1024
        float a0 = (float)sidx * expf(cfac * (float)(d0));
        float a1 = (float)sidx * expf(cfac * (float)(d0 + 2));
        o0 += sinf(a0); o1 += cosf(a0);
        o2 += sinf(a1); o3 += cosf(a1);
    }
    ushort4 o;
    o.x = f2b(o0); o.y = f2b(o1); o.z = f2b(o2); o.w = f2b(o3);
    *(ushort4*)(out + (size_t)row*DD + d0) = o;
}

// ---------------------------------------------------------------- bf16 MFMA GEMM  C = A[M,K] * Bt[N,K]^T
// Proven round-1 structure: 128x128, 2-phase, (256,2).  928 TF on the w2 shape.
template<int EPI>
__global__ __launch_bounds__(256, 2) void gemm_bt(
        const unsigned short* __restrict__ A,
        const unsigned short* __restrict__ Bt,
        void* __restrict__ Cout,
        const float* __restrict__ bias,
        const void* __restrict__ resid,
        int M, int N, int K)
{
    __shared__ __align__(16) unsigned short lA[128*64];
    __shared__ __align__(16) unsigned short lB[128*64];
    const int tid  = threadIdx.x;
    const int lane = tid & 63;
    const int wave = tid >> 6;
    const int quad = lane >> 4;
    const int l16  = lane & 15;
    const int wr = wave >> 1, wc = wave & 1;

    // XCD-aware tile swizzle (m-tiles divisible by 8 here)
    int gn  = gridDim.x;
    int lin = blockIdx.y * gn + blockIdx.x;
    int xcd = lin & 7;
    int j   = lin >> 3;
    int mt  = xcd + 8*(j/gn);
    int nt  = j - (j/gn)*gn;
    const int m0 = mt * 128;
    const int n0 = nt * 128;

    f32x4 acc[4][4] = {};

    for (int k0 = 0; k0 < K; k0 += 64) {
        __syncthreads();
        #pragma unroll
        for (int i = 0; i < 4; i++) {
            int c   = tid + 256*i;
            int row = c >> 3;
            int kc  = ((c & 7) ^ (row & 7)) << 3;          // XOR swizzle (elements)
            const unsigned short* gA = A  + (size_t)(m0 + row) * K + k0 + kc;
            const unsigned short* gB = Bt + (size_t)(n0 + row) * K + k0 + kc;
            char* lpA = ((char*)lA) + (wave<<10) + (i<<12); // wave-uniform base; HW adds lane*16
            char* lpB = ((char*)lB) + (wave<<10) + (i<<12);
            __builtin_amdgcn_global_load_lds((const __attribute__((address_space(1))) void*)gA,
                                             (__attribute__((address_space(3))) void*)lpA, 16, 0, 0);
            __builtin_amdgcn_global_load_lds((const __attribute__((address_space(1))) void*)gB,
                                             (__attribute__((address_space(3))) void*)lpB, 16, 0, 0);
        }
        __syncthreads();
        #pragma unroll
        for (int kk = 0; kk < 2; kk++) {
            bf16x8 af[4], bfr[4];
            #pragma unroll
            for (int mi = 0; mi < 4; mi++) {
                int row = wr*64 + mi*16 + l16;
                int kb  = (kk*64 + quad*16) ^ ((row & 7) << 4);
                af[mi] = *(const bf16x8*)((const char*)lA + row*128 + kb);
            }
            #pragma unroll
            for (int ni = 0; ni < 4; ni++) {
                int row = wc*64 + ni*16 + l16;
                int kb  = (kk*64 + quad*16) ^ ((row & 7) << 4);
                bfr[ni] = *(const bf16x8*)((const char*)lB + row*128 + kb);
            }
            #pragma unroll
            for (int mi = 0; mi < 4; mi++)
                #pragma unroll
                for (int ni = 0; ni < 4; ni++)
                    acc[mi][ni] = __builtin_amdgcn_mfma_f32_16x16x32_bf16(af[mi], bfr[ni], acc[mi][ni], 0, 0, 0);
        }
    }

    #pragma unroll
    for (int mi = 0; mi < 4; mi++) {
        #pragma unroll
        for (int r = 0; r < 4; r++) {
            int grow = m0 + wr*64 + mi*16 + quad*4 + r;
            #pragma unroll
            for (int ni = 0; ni < 4; ni++) {
                int gcol = n0 + wc*64 + ni*16 + l16;
                float v = acc[mi][ni][r];
                size_t idx = (size_t)grow * N + gcol;
                if (EPI == 0) {
                    ((unsigned short*)Cout)[idx] = f2b(v);
                } else if (EPI == 1) {
                    v += bias[gcol];
                    v = 0.5f * v * (1.0f + erff(v * 0.70710678118654752f));
                    ((unsigned short*)Cout)[idx] = f2b(v);
                } else if (EPI == 2) {
                    v += bias[gcol] + ((const float*)resid)[idx];
                    ((unsigned short*)Cout)[idx] = f2b(v);
                } else {
                    v += bias[gcol] + b2f(((const unsigned short*)resid)[idx]);
                    ((float*)Cout)[idx] = v;
                }
            }
        }
    }
}

// ---------------------------------------------------------------- context partials (k-softmax folded)
// 1-wave blocks, 8x8 per-lane tile: 4 ds_read_b128 per 64 FMA (2x fewer LDS insts than 4x4/4-wave).
// E_slot[d,e] = sum_s exp(k[s,d]) * v[s,e] ;  cs_slot[d] = sum_s exp(k[s,d])
__global__ __launch_bounds__(64) void ctx_partial(const unsigned short* __restrict__ qkv,
                                                  float* __restrict__ EP,
                                                  float* __restrict__ CS){
    int sc = blockIdx.x, h = blockIdx.y, b = blockIdx.z;
    int l = threadIdx.x;
    __shared__ __align__(16) float kl[64][64];   // exp(k)
    __shared__ __align__(16) float vl[64][64];
    float acc[8][8] = {};
    float csacc = 0.0f;
    const int d8 = (l >> 3) * 8, e8 = (l & 7) * 8;
    for(int s0 = 0; s0 < 256; s0 += 64){
        __syncthreads();
        #pragma unroll
        for(int j=0;j<8;j++){
            int lin = l + 64*j;
            int row = lin >> 3;
            int c8  = (lin & 7) * 8;
            size_t gr = (size_t)(b*SS + sc*256 + s0 + row);
            uint4 kv = *(const uint4*)(qkv + gr*3072 + DD + h*64 + c8);
            float4 ka, kb2;
            ka.x = expf(b2f_u(kv.x & 0xFFFFu)); ka.y = expf(b2f_u(kv.x >> 16));
            ka.z = expf(b2f_u(kv.y & 0xFFFFu)); ka.w = expf(b2f_u(kv.y >> 16));
            kb2.x = expf(b2f_u(kv.z & 0xFFFFu)); kb2.y = expf(b2f_u(kv.z >> 16));
            kb2.z = expf(b2f_u(kv.w & 0xFFFFu)); kb2.w = expf(b2f_u(kv.w >> 16));
            *(float4*)&kl[row][c8]   = ka;
            *(float4*)&kl[row][c8+4] = kb2;
            uint4 vv = *(const uint4*)(qkv + gr*3072 + 2*DD + h*64 + c8);
            float4 va, vb;
            va.x = b2f_u(vv.x & 0xFFFFu); va.y = b2f_u(vv.x >> 16);
            va.z = b2f_u(vv.y & 0xFFFFu); va.w = b2f_u(vv.y >> 16);
            vb.x = b2f_u(vv.z & 0xFFFFu); vb.y = b2f_u(vv.z >> 16);
            vb.z = b2f_u(vv.w & 0xFFFFu); vb.w = b2f_u(vv.w >> 16);
            *(float4*)&vl[row][c8]   = va;
            *(float4*)&vl[row][c8+4] = vb;
        }
        __syncthreads();
        // column sum: lane l owns column l (conflict-free: 2 lanes/bank)
        #pragma unroll 8
        for(int s=0;s<64;s++) csacc += kl[s][l];
        // 8x8 register tile
        for(int s=0;s<64;s++){
            float4 ka = *(const float4*)&kl[s][d8];
            float4 kb2 = *(const float4*)&kl[s][d8+4];
            float4 va = *(const float4*)&vl[s][e8];
            float4 vb = *(const float4*)&vl[s][e8+4];
            float kv8[8] = {ka.x,ka.y,ka.z,ka.w,kb2.x,kb2.y,kb2.z,kb2.w};
            float vv8[8] = {va.x,va.y,va.z,va.w,vb.x,vb.y,vb.z,vb.w};
            #pragma unroll
            for(int i=0;i<8;i++)
                #pragma unroll
                for(int jj=0;jj<8;jj++)
                    acc[i][jj] += kv8[i]*vv8[jj];
        }
    }
    int slot = (b*HH + h)*16 + sc;
    float* ep = EP + (size_t)slot*4096;
    #pragma unroll
    for(int i=0;i<8;i++){
        float4 o1, o2;
        o1.x=acc[i][0]; o1.y=acc[i][1]; o1.z=acc[i][2]; o1.w=acc[i][3];
        o2.x=acc[i][4]; o2.y=acc[i][5]; o2.z=acc[i][6]; o2.w=acc[i][7];
        *(float4*)&ep[(d8+i)*64 + e8]     = o1;
        *(float4*)&ep[(d8+i)*64 + e8 + 4] = o2;
    }
    CS[slot*64 + l] = csacc;
}

// ---------------------------------------------------------------- reduce 16 slots, divide by colsum
__global__ __launch_bounds__(256) void ctx_reduce(const float* __restrict__ EP,
                                                  const float* __restrict__ CS,
                                                  float* __restrict__ CTXF){
    int bh = blockIdx.x;
    int t = threadIdx.x;
    int d = t >> 2, e0 = (t & 3) * 16;
    float cs = 0.0f;
    #pragma unroll
    for(int sl=0; sl<16; sl++) cs += CS[(bh*16+sl)*64 + d];
    float inv = 1.0f/cs;
    #pragma unroll
    for(int i=0;i<16;i++){
        float s = 0.0f;
        #pragma unroll
        for(int sl=0; sl<16; sl++) s += EP[(size_t)(bh*16+sl)*4096 + d*64 + e0 + i];
        CTXF[(size_t)bh*4096 + d*64 + e0 + i] = s * inv;
    }
}

// ---------------------------------------------------------------- attn = softmax(q)/8 @ ctx  (q-softmax fused)
// 1-wave blocks, 8x8 per-lane tile; softmax fully in-register (lane = row, no shuffles).
__global__ __launch_bounds__(64) void attn_heads(const unsigned short* __restrict__ qkv,
                                                 const float* __restrict__ CTXF,
                                                 unsigned short* __restrict__ abuf){
    int rg = blockIdx.x, h = blockIdx.y;
    int b = rg >> 6;
    int l = threadIdx.x;
    __shared__ __align__(16) float cl[64][64];   // ctx
    __shared__ __align__(16) float qT[64][64];   // [d][r]
    const float* cb = CTXF + (size_t)(b*HH + h)*4096;
    #pragma unroll
    for(int j=0;j<16;j++){
        int lin = l + 64*j;
        ((float4*)cl)[lin] = ((const float4*)cb)[lin];
    }
    // lane l owns q-row rg*64+l: load 64 values, softmax in registers, store transposed+scaled
    {
        const unsigned short* qp = qkv + (size_t)(rg*64 + l)*3072 + h*64;
        float vals[64];
        #pragma unroll
        for(int u=0; u<16; u++){
            ushort4 qv = *(const ushort4*)(qp + u*4);
            vals[u*4+0]=b2f(qv.x); vals[u*4+1]=b2f(qv.y); vals[u*4+2]=b2f(qv.z); vals[u*4+3]=b2f(qv.w);
        }
        float m = vals[0];
        #pragma unroll
        for(int i=1;i<64;i++) m = fmaxf(m, vals[i]);
        float ssum = 0.0f;
        #pragma unroll
        for(int i=0;i<64;i++){ vals[i] = expf(vals[i]-m); ssum += vals[i]; }
        float scl = 0.125f/ssum;
        #pragma unroll
        for(int d=0; d<64; d++) qT[d][l] = vals[d]*scl;
    }
    __syncthreads();
    const int r8 = (l >> 3) * 8, e8 = (l & 7) * 8;
    float acc[8][8] = {};
    for(int d=0; d<64; d++){
        float4 qa = *(const float4*)&qT[d][r8];
        float4 qb = *(const float4*)&qT[d][r8+4];
        float4 ca = *(const float4*)&cl[d][e8];
        float4 cb2 = *(const float4*)&cl[d][e8+4];
        float q8[8] = {qa.x,qa.y,qa.z,qa.w,qb.x,qb.y,qb.z,qb.w};
        float c8v[8] = {ca.x,ca.y,ca.z,ca.w,cb2.x,cb2.y,cb2.z,cb2.w};
        #pragma unroll
        for(int i=0;i<8;i++)
            #pragma unroll
            for(int jj=0;jj<8;jj++)
                acc[i][jj] += q8[i]*c8v[jj];
    }
    #pragma unroll
    for(int i=0;i<8;i++){
        ushort4 o1, o2;
        o1.x = f2b(acc[i][0]); o1.y = f2b(acc[i][1]); o1.z = f2b(acc[i][2]); o1.w = f2b(acc[i][3]);
        o2.x = f2b(acc[i][4]); o2.y = f2b(acc[i][5]); o2.z = f2b(acc[i][6]); o2.w = f2b(acc[i][7]);
        unsigned short* op = abuf + (size_t)(rg*64 + r8 + i)*DD + h*64 + e8;
        *(ushort4*)op       = o1;
        *(ushort4*)(op + 4) = o2;
    }
}

// ---------------------------------------------------------------- launch
extern "C" void kernel_launch(void* const* d_in, const int* in_sizes, int n_in,
                              void* d_out, int out_size, void* d_ws, size_t ws_size,
                              hipStream_t stream)
{
    const float* x     = (const float*)d_in[0];
    const float* ln1_g = (const float*)d_in[1];
    const float* ln1_b = (const float*)d_in[2];
    const float* w_qkv = (const float*)d_in[3];
    const float* w_out = (const float*)d_in[4];
    const float* b_out = (const float*)d_in[5];
    const float* ln2_g = (const float*)d_in[6];
    const float* ln2_b = (const float*)d_in[7];
    const float* w1    = (const float*)d_in[8];
    const float* b1    = (const float*)d_in[9];
    const float* w2    = (const float*)d_in[10];
    const float* b2    = (const float*)d_in[11];
    const float* w3    = (const float*)d_in[12];
    const float* b3    = (const float*)d_in[13];

    // ---- workspace layout (aliases temporally disjoint) ----
    char* ws = (char*)d_ws;
    unsigned short* wqkvT = (unsigned short*)(ws + 0);            // 6291456 B
    unsigned short* woutT = (unsigned short*)(ws + 6291456);      // 2097152 B
    unsigned short* w1T   = (unsigned short*)(ws + 8388608);      // 4194304 B
    unsigned short* w2T   = (unsigned short*)(ws + 12582912);     // 8388608 B
    unsigned short* w3T   = (unsigned short*)(ws + 20971520);     // 4194304 B
    unsigned short* Hbuf  = (unsigned short*)(ws + 25165824);     // 32 MB (ln1 out; later Abuf/H2)
    unsigned short* QKV   = (unsigned short*)(ws + 58720256);     // 96 MB (dead after attn_heads)
    float*          EP    = (float*)(ws + 159383552);             // 16 MB (attn phase)
    float*          CS    = (float*)(ws + 176160768);             // 256 KB
    float*          CTXF  = (float*)(ws + 176422912);             // 1 MB
    // phase 2 aliases:
    unsigned short* Abuf  = Hbuf;
    unsigned short* X2    = (unsigned short*)(ws + 58720256);     // x+attn bf16 [M,1024] (alias QKV head)
    unsigned short* H2    = Hbuf;
    unsigned short* Y1    = (unsigned short*)d_out;               // [M,2048] bf16 = out buffer
    unsigned short* Y2    = (unsigned short*)(ws + 125829120);    // 64 MB (alias QKV tail / EP region)

    transpose_cvt_all<<<12288, 256, 0, stream>>>(w_qkv, w_out, w1, w2, w3,
                                                 wqkvT, woutT, w1T, w2T, w3T);

    ln_kernel<0><<<MM, 256, 0, stream>>>(x, ln1_g, ln1_b, Hbuf, 1);

    gemm_bt<0><<<dim3(3072/128, MM/128), 256, 0, stream>>>(Hbuf, wqkvT, QKV, nullptr, nullptr, MM, 3072, 1024);

    ctx_partial<<<dim3(16, HH, BB), 64, 0, stream>>>(QKV, EP, CS);
    ctx_reduce<<<BB*HH, 256, 0, stream>>>(EP, CS, CTXF);
    attn_heads<<<dim3(256, HH), 64, 0, stream>>>(QKV, CTXF, Abuf);

    gemm_bt<2><<<dim3(1024/128, MM/128), 256, 0, stream>>>(Abuf, woutT, X2, b_out, x, MM, 1024, 1024);

    ln_kernel<1><<<MM, 256, 0, stream>>>(X2, ln2_g, ln2_b, H2, 0);

    gemm_bt<1><<<dim3(2048/128, MM/128), 256, 0, stream>>>(H2, w1T, Y1, b1, nullptr, MM, 2048, 1024);
    gemm_bt<1><<<dim3(2048/128, MM/128), 256, 0, stream>>>(Y1, w2T, Y2, b2, nullptr, MM, 2048, 2048);
    gemm_bt<3><<<dim3(1024/128, MM/128), 256, 0, stream>>>(Y2, w3T, d_out, b3, X2, MM, 1024, 2048);
}

// Round 7
// 713.192 us; speedup vs baseline: 1.1520x; 1.0499x over previous
//
#include <hip/hip_runtime.h>
#include <cstdint>
#include <cstddef>

// Problem constants
#define BB 4
#define SS 4096
#define DD 1024
#define HH 16
#define MM (BB*SS)          // 16384 rows

typedef __bf16 bf16x8 __attribute__((ext_vector_type(8)));
typedef float  f32x4  __attribute__((ext_vector_type(4)));

__device__ __forceinline__ float b2f(unsigned short h){
    union { unsigned int u; float f; } c; c.u = ((unsigned int)h) << 16; return c.f;
}
__device__ __forceinline__ float b2f_u(unsigned int u16){
    union { unsigned int u; float f; } c; c.u = u16 << 16; return c.f;
}
__device__ __forceinline__ unsigned short f2b(float f){
    union { float f; unsigned int u; } c; c.f = f;
    unsigned int u = c.u + 0x7FFFu + ((c.u >> 16) & 1u);   // RNE
    return (unsigned short)(u >> 16);
}

// ---------------------------------------------------------------- fused transpose+cvt for all 5 weights
__global__ __launch_bounds__(256) void transpose_cvt_all(
        const float* __restrict__ wqkv, const float* __restrict__ wout,
        const float* __restrict__ w1,   const float* __restrict__ w2,
        const float* __restrict__ w3,
        unsigned short* __restrict__ dqkv, unsigned short* __restrict__ dout,
        unsigned short* __restrict__ d1,   unsigned short* __restrict__ d2,
        unsigned short* __restrict__ d3)
{
    int id = blockIdx.x;
    const float* src; unsigned short* dst; int K, N, bx, by;
    if (id < 3072)       { src=wqkv; dst=dqkv; K=1024; N=3072; int r=id;        bx=r%96; by=r/96; }
    else if (id < 4096)  { src=wout; dst=dout; K=1024; N=1024; int r=id-3072;   bx=r%32; by=r/32; }
    else if (id < 6144)  { src=w1;   dst=d1;   K=1024; N=2048; int r=id-4096;   bx=r%64; by=r/64; }
    else if (id < 10240) { src=w2;   dst=d2;   K=2048; N=2048; int r=id-6144;   bx=r%64; by=r/64; }
    else                 { src=w3;   dst=d3;   K=2048; N=1024; int r=id-10240;  bx=r%32; by=r/32; }

    __shared__ float tile[32][33];
    int kb = by*32, nb = bx*32;
    int tx = threadIdx.x & 31, ty = threadIdx.x >> 5;
    for(int i=0;i<32;i+=8) tile[ty+i][tx] = src[(size_t)(kb+ty+i)*N + nb+tx];
    __syncthreads();
    for(int i=0;i<32;i+=8) dst[(size_t)(nb+ty+i)*K + kb+tx] = f2b(tile[tx][ty+i]);
}

// ---------------------------------------------------------------- layernorm (+ optional sinusoidal PE)
template<int INBF>
__global__ __launch_bounds__(256) void ln_kernel(const void* __restrict__ xin,
                                                 const float* __restrict__ g,
                                                 const float* __restrict__ bta,
                                                 unsigned short* __restrict__ out,
                                                 int add_pe){
    int row = blockIdx.x;
    int t = threadIdx.x;
    float4 v;
    if (INBF == 0) {
        v = ((const float4*)((const float*)xin + (size_t)row*DD))[t];
    } else {
        ushort4 u = ((const ushort4*)((const unsigned short*)xin + (size_t)row*DD))[t];
        v.x = b2f(u.x); v.y = b2f(u.y); v.z = b2f(u.z); v.w = b2f(u.w);
    }
    float s = v.x+v.y+v.z+v.w;
    float q = v.x*v.x+v.y*v.y+v.z*v.z+v.w*v.w;
    for(int off=32; off>0; off>>=1){ s += __shfl_xor(s, off); q += __shfl_xor(q, off); }
    __shared__ float red[8];
    int wv = t>>6, ln = t&63;
    if(ln==0){ red[wv] = s; red[4+wv] = q; }
    __syncthreads();
    s = red[0]+red[1]+red[2]+red[3];
    q = red[4]+red[5]+red[6]+red[7];
    float mu = s * (1.0f/1024.0f);
    float var = q * (1.0f/1024.0f) - mu*mu;
    float rs = rsqrtf(var + 1e-6f);
    int d0 = t*4;
    float4 gg = ((const float4*)g)[t];
    float4 bb = ((const float4*)bta)[t];
    float o0 = (v.x-mu)*rs*gg.x + bb.x;
    float o1 = (v.y-mu)*rs*gg.y + bb.y;
    float o2 = (v.z-mu)*rs*gg.z + bb.z;
    float o3 = (v.w-mu)*rs*gg.w + bb.w;
    if(add_pe){
        int sidx = row & (SS-1);
        const float cfac = -0.008994473019508968f;   // -ln(10000)/1024
        float a0 = (float)sidx * expf(cfac * (float)(d0));
        float a1 = (float)sidx * expf(cfac * (float)(d0 + 2));
        o0 += sinf(a0); o1 += cosf(a0);
        o2 += sinf(a1); o3 += cosf(a1);
    }
    ushort4 o;
    o.x = f2b(o0); o.y = f2b(o1); o.z = f2b(o2); o.w = f2b(o3);
    *(ushort4*)(out + (size_t)row*DD + d0) = o;
}

// ---------------------------------------------------------------- bf16 MFMA GEMM  C = A[M,K] * Bt[N,K]^T
// Proven round-1 structure: 128x128, 2-phase, (256,2).  ~928 TF on the w2 shape.
template<int EPI>
__global__ __launch_bounds__(256, 2) void gemm_bt(
        const unsigned short* __restrict__ A,
        const unsigned short* __restrict__ Bt,
        void* __restrict__ Cout,
        const float* __restrict__ bias,
        const void* __restrict__ resid,
        int M, int N, int K)
{
    __shared__ __align__(16) unsigned short lA[128*64];
    __shared__ __align__(16) unsigned short lB[128*64];
    const int tid  = threadIdx.x;
    const int lane = tid & 63;
    const int wave = tid >> 6;
    const int quad = lane >> 4;
    const int l16  = lane & 15;
    const int wr = wave >> 1, wc = wave & 1;

    // XCD-aware tile swizzle (m-tiles divisible by 8 here)
    int gn  = gridDim.x;
    int lin = blockIdx.y * gn + blockIdx.x;
    int xcd = lin & 7;
    int j   = lin >> 3;
    int mt  = xcd + 8*(j/gn);
    int nt  = j - (j/gn)*gn;
    const int m0 = mt * 128;
    const int n0 = nt * 128;

    f32x4 acc[4][4] = {};

    for (int k0 = 0; k0 < K; k0 += 64) {
        __syncthreads();
        #pragma unroll
        for (int i = 0; i < 4; i++) {
            int c   = tid + 256*i;
            int row = c >> 3;
            int kc  = ((c & 7) ^ (row & 7)) << 3;          // XOR swizzle (elements)
            const unsigned short* gA = A  + (size_t)(m0 + row) * K + k0 + kc;
            const unsigned short* gB = Bt + (size_t)(n0 + row) * K + k0 + kc;
            char* lpA = ((char*)lA) + (wave<<10) + (i<<12); // wave-uniform base; HW adds lane*16
            char* lpB = ((char*)lB) + (wave<<10) + (i<<12);
            __builtin_amdgcn_global_load_lds((const __attribute__((address_space(1))) void*)gA,
                                             (__attribute__((address_space(3))) void*)lpA, 16, 0, 0);
            __builtin_amdgcn_global_load_lds((const __attribute__((address_space(1))) void*)gB,
                                             (__attribute__((address_space(3))) void*)lpB, 16, 0, 0);
        }
        __syncthreads();
        #pragma unroll
        for (int kk = 0; kk < 2; kk++) {
            bf16x8 af[4], bfr[4];
            #pragma unroll
            for (int mi = 0; mi < 4; mi++) {
                int row = wr*64 + mi*16 + l16;
                int kb  = (kk*64 + quad*16) ^ ((row & 7) << 4);
                af[mi] = *(const bf16x8*)((const char*)lA + row*128 + kb);
            }
            #pragma unroll
            for (int ni = 0; ni < 4; ni++) {
                int row = wc*64 + ni*16 + l16;
                int kb  = (kk*64 + quad*16) ^ ((row & 7) << 4);
                bfr[ni] = *(const bf16x8*)((const char*)lB + row*128 + kb);
            }
            #pragma unroll
            for (int mi = 0; mi < 4; mi++)
                #pragma unroll
                for (int ni = 0; ni < 4; ni++)
                    acc[mi][ni] = __builtin_amdgcn_mfma_f32_16x16x32_bf16(af[mi], bfr[ni], acc[mi][ni], 0, 0, 0);
        }
    }

    #pragma unroll
    for (int mi = 0; mi < 4; mi++) {
        #pragma unroll
        for (int r = 0; r < 4; r++) {
            int grow = m0 + wr*64 + mi*16 + quad*4 + r;
            #pragma unroll
            for (int ni = 0; ni < 4; ni++) {
                int gcol = n0 + wc*64 + ni*16 + l16;
                float v = acc[mi][ni][r];
                size_t idx = (size_t)grow * N + gcol;
                if (EPI == 0) {
                    ((unsigned short*)Cout)[idx] = f2b(v);
                } else if (EPI == 1) {
                    v += bias[gcol];
                    v = 0.5f * v * (1.0f + erff(v * 0.70710678118654752f));
                    ((unsigned short*)Cout)[idx] = f2b(v);
                } else if (EPI == 2) {
                    v += bias[gcol] + ((const float*)resid)[idx];
                    ((unsigned short*)Cout)[idx] = f2b(v);
                } else {
                    v += bias[gcol] + b2f(((const unsigned short*)resid)[idx]);
                    ((float*)Cout)[idx] = v;
                }
            }
        }
    }
}

// ---------------------------------------------------------------- context partials (k-softmax folded)
// 256 threads / 4 waves (occupancy preserved).  Wave-split over s: wave w handles
// s = w*16..w*16+15 of each 64-chunk with an 8x8 per-lane tile over the FULL 64x64
// output; cross-wave register-tile reduce at the end via LDS scratch.
// Main-loop LDS insts: 1024 b128/block (vs 2048 in the 4x4/4-wave version).
__global__ __launch_bounds__(256) void ctx_partial(const unsigned short* __restrict__ qkv,
                                                   float* __restrict__ EP,
                                                   float* __restrict__ CS){
    int sc = blockIdx.x, h = blockIdx.y, b = blockIdx.z;
    int t = threadIdx.x;
    int w = t >> 6, l = t & 63;
    __shared__ __align__(16) float kl[64][64];   // exp(k)
    __shared__ __align__(16) float vl[64][64];
    __shared__ float csred[4][64];
    float acc[8][8] = {};
    float cspart = 0.0f;
    const int d8 = (l >> 3) * 8, e8 = (l & 7) * 8;
    for(int s0 = 0; s0 < 256; s0 += 64){
        __syncthreads();
        #pragma unroll
        for(int j=0;j<2;j++){
            int lin = t + 256*j;
            int row = lin >> 3;
            int c8  = (lin & 7) * 8;
            size_t gr = (size_t)(b*SS + sc*256 + s0 + row);
            uint4 kv = *(const uint4*)(qkv + gr*3072 + DD + h*64 + c8);
            float4 ka, kb2;
            ka.x = expf(b2f_u(kv.x & 0xFFFFu)); ka.y = expf(b2f_u(kv.x >> 16));
            ka.z = expf(b2f_u(kv.y & 0xFFFFu)); ka.w = expf(b2f_u(kv.y >> 16));
            kb2.x = expf(b2f_u(kv.z & 0xFFFFu)); kb2.y = expf(b2f_u(kv.z >> 16));
            kb2.z = expf(b2f_u(kv.w & 0xFFFFu)); kb2.w = expf(b2f_u(kv.w >> 16));
            *(float4*)&kl[row][c8]   = ka;
            *(float4*)&kl[row][c8+4] = kb2;
            uint4 vv = *(const uint4*)(qkv + gr*3072 + 2*DD + h*64 + c8);
            float4 va, vb;
            va.x = b2f_u(vv.x & 0xFFFFu); va.y = b2f_u(vv.x >> 16);
            va.z = b2f_u(vv.y & 0xFFFFu); va.w = b2f_u(vv.y >> 16);
            vb.x = b2f_u(vv.z & 0xFFFFu); vb.y = b2f_u(vv.z >> 16);
            vb.z = b2f_u(vv.w & 0xFFFFu); vb.w = b2f_u(vv.w >> 16);
            *(float4*)&vl[row][c8]   = va;
            *(float4*)&vl[row][c8+4] = vb;
        }
        __syncthreads();
        // colsum: wave w sums its 16 rows of column l (same split as round-1)
        #pragma unroll
        for(int i=0;i<16;i++) cspart += kl[w*16+i][l];
        // 8x8 tile over this wave's s-subset
        #pragma unroll 4
        for(int si=0; si<16; si++){
            int s = w*16 + si;
            float4 ka  = *(const float4*)&kl[s][d8];
            float4 kb2 = *(const float4*)&kl[s][d8+4];
            float4 va  = *(const float4*)&vl[s][e8];
            float4 vb  = *(const float4*)&vl[s][e8+4];
            float kv8[8] = {ka.x,ka.y,ka.z,ka.w,kb2.x,kb2.y,kb2.z,kb2.w};
            float vv8[8] = {va.x,va.y,va.z,va.w,vb.x,vb.y,vb.z,vb.w};
            #pragma unroll
            for(int i=0;i<8;i++)
                #pragma unroll
                for(int jj=0;jj<8;jj++)
                    acc[i][jj] += kv8[i]*vv8[jj];
        }
    }
    csred[w][l] = cspart;
    __syncthreads();                         // all compute reads of kl/vl done
    // cross-wave reduce of acc (reuse kl/vl as scratch; [j][l] b32 layout, conflict-free)
    float* r0 = (float*)kl;
    float* r1 = (float*)vl;
    if(w == 2){
        #pragma unroll
        for(int j=0;j<64;j++) r0[j*64 + l] = acc[j>>3][j&7];
    } else if(w == 3){
        #pragma unroll
        for(int j=0;j<64;j++) r1[j*64 + l] = acc[j>>3][j&7];
    }
    __syncthreads();
    if(w == 0){
        #pragma unroll
        for(int j=0;j<64;j++) acc[j>>3][j&7] += r0[j*64 + l];
    } else if(w == 1){
        #pragma unroll
        for(int j=0;j<64;j++) acc[j>>3][j&7] += r1[j*64 + l];
    }
    __syncthreads();
    if(w == 1){
        #pragma unroll
        for(int j=0;j<64;j++) r0[j*64 + l] = acc[j>>3][j&7];
    }
    __syncthreads();
    int slot = (b*HH + h)*16 + sc;
    if(w == 0){
        #pragma unroll
        for(int j=0;j<64;j++) acc[j>>3][j&7] += r0[j*64 + l];
        float* ep = EP + (size_t)slot*4096;
        #pragma unroll
        for(int i=0;i<8;i++){
            float4 o1, o2;
            o1.x=acc[i][0]; o1.y=acc[i][1]; o1.z=acc[i][2]; o1.w=acc[i][3];
            o2.x=acc[i][4]; o2.y=acc[i][5]; o2.z=acc[i][6]; o2.w=acc[i][7];
            *(float4*)&ep[(d8+i)*64 + e8]     = o1;
            *(float4*)&ep[(d8+i)*64 + e8 + 4] = o2;
        }
    }
    if(t < 64) CS[slot*64 + t] = csred[0][t]+csred[1][t]+csred[2][t]+csred[3][t];
}

// ---------------------------------------------------------------- reduce 16 slots, divide by colsum
__global__ __launch_bounds__(256) void ctx_reduce(const float* __restrict__ EP,
                                                  const float* __restrict__ CS,
                                                  float* __restrict__ CTXF){
    int bh = blockIdx.x;
    int t = threadIdx.x;
    int d = t >> 2, e0 = (t & 3) * 16;
    float cs = 0.0f;
    #pragma unroll
    for(int sl=0; sl<16; sl++) cs += CS[(bh*16+sl)*64 + d];
    float inv = 1.0f/cs;
    #pragma unroll
    for(int i=0;i<16;i++){
        float s = 0.0f;
        #pragma unroll
        for(int sl=0; sl<16; sl++) s += EP[(size_t)(bh*16+sl)*4096 + d*64 + e0 + i];
        CTXF[(size_t)bh*4096 + d*64 + e0 + i] = s * inv;
    }
}

// ---------------------------------------------------------------- attn = softmax(q)/8 @ ctx  (q-softmax fused)
// 256 threads / 4 waves.  Softmax identical to round-1 (4 lanes per q-row, shuffles).
// Matmul wave-split over d: wave w handles d = w*16..w*16+15 with 8x8 per-lane tile;
// cross-wave reduce via LDS scratch.  Main-loop LDS insts: 256 b128/block (vs 512).
__global__ __launch_bounds__(256) void attn_heads(const unsigned short* __restrict__ qkv,
                                                  const float* __restrict__ CTXF,
                                                  unsigned short* __restrict__ abuf){
    int rg = blockIdx.x, h = blockIdx.y;
    int b = rg >> 6;
    int t = threadIdx.x;
    int w = t >> 6, l = t & 63;
    __shared__ __align__(16) float cl[64][64];   // ctx
    __shared__ __align__(16) float qT[64][64];   // [d][r]
    const float* cb = CTXF + (size_t)(b*HH + h)*4096;
    #pragma unroll
    for(int j=0;j<4;j++){
        int lin = t + 256*j;
        ((float4*)cl)[lin] = ((const float4*)cb)[lin];
    }
    // load q row-segment, softmax in registers, store transposed+scaled to LDS
    {
        int r = t >> 2, seg = (t & 3) * 16;
        const unsigned short* qp = qkv + (size_t)(rg*64 + r)*3072 + h*64 + seg;
        float vals[16];
        float m = -1e30f;
        #pragma unroll
        for(int u=0; u<4; u++){
            ushort4 qv = *(const ushort4*)(qp + u*4);
            vals[u*4+0]=b2f(qv.x); vals[u*4+1]=b2f(qv.y); vals[u*4+2]=b2f(qv.z); vals[u*4+3]=b2f(qv.w);
        }
        #pragma unroll
        for(int i=0;i<16;i++) m = fmaxf(m, vals[i]);
        m = fmaxf(m, __shfl_xor(m, 1));
        m = fmaxf(m, __shfl_xor(m, 2));
        float ssum = 0.0f;
        #pragma unroll
        for(int i=0;i<16;i++){ vals[i] = expf(vals[i]-m); ssum += vals[i]; }
        ssum += __shfl_xor(ssum, 1);
        ssum += __shfl_xor(ssum, 2);
        float scl = 0.125f/ssum;
        #pragma unroll
        for(int i=0;i<16;i++) qT[seg+i][r] = vals[i]*scl;
    }
    __syncthreads();
    const int r8 = (l >> 3) * 8, e8 = (l & 7) * 8;
    float acc[8][8] = {};
    #pragma unroll 4
    for(int di=0; di<16; di++){
        int d = w*16 + di;
        float4 qa  = *(const float4*)&qT[d][r8];
        float4 qb  = *(const float4*)&qT[d][r8+4];
        float4 ca  = *(const float4*)&cl[d][e8];
        float4 cb2 = *(const float4*)&cl[d][e8+4];
        float q8[8]  = {qa.x,qa.y,qa.z,qa.w,qb.x,qb.y,qb.z,qb.w};
        float c8v[8] = {ca.x,ca.y,ca.z,ca.w,cb2.x,cb2.y,cb2.z,cb2.w};
        #pragma unroll
        for(int i=0;i<8;i++)
            #pragma unroll
            for(int jj=0;jj<8;jj++)
                acc[i][jj] += q8[i]*c8v[jj];
    }
    __syncthreads();                         // all reads of cl/qT done
    float* r0 = (float*)cl;
    float* r1 = (float*)qT;
    if(w == 2){
        #pragma unroll
        for(int j=0;j<64;j++) r0[j*64 + l] = acc[j>>3][j&7];
    } else if(w == 3){
        #pragma unroll
        for(int j=0;j<64;j++) r1[j*64 + l] = acc[j>>3][j&7];
    }
    __syncthreads();
    if(w == 0){
        #pragma unroll
        for(int j=0;j<64;j++) acc[j>>3][j&7] += r0[j*64 + l];
    } else if(w == 1){
        #pragma unroll
        for(int j=0;j<64;j++) acc[j>>3][j&7] += r1[j*64 + l];
    }
    __syncthreads();
    if(w == 1){
        #pragma unroll
        for(int j=0;j<64;j++) r0[j*64 + l] = acc[j>>3][j&7];
    }
    __syncthreads();
    if(w == 0){
        #pragma unroll
        for(int j=0;j<64;j++) acc[j>>3][j&7] += r0[j*64 + l];
        #pragma unroll
        for(int i=0;i<8;i++){
            ushort4 o1, o2;
            o1.x = f2b(acc[i][0]); o1.y = f2b(acc[i][1]); o1.z = f2b(acc[i][2]); o1.w = f2b(acc[i][3]);
            o2.x = f2b(acc[i][4]); o2.y = f2b(acc[i][5]); o2.z = f2b(acc[i][6]); o2.w = f2b(acc[i][7]);
            unsigned short* op = abuf + (size_t)(rg*64 + r8 + i)*DD + h*64 + e8;
            *(ushort4*)op       = o1;
            *(ushort4*)(op + 4) = o2;
        }
    }
}

// ---------------------------------------------------------------- launch
extern "C" void kernel_launch(void* const* d_in, const int* in_sizes, int n_in,
                              void* d_out, int out_size, void* d_ws, size_t ws_size,
                              hipStream_t stream)
{
    const float* x     = (const float*)d_in[0];
    const float* ln1_g = (const float*)d_in[1];
    const float* ln1_b = (const float*)d_in[2];
    const float* w_qkv = (const float*)d_in[3];
    const float* w_out = (const float*)d_in[4];
    const float* b_out = (const float*)d_in[5];
    const float* ln2_g = (const float*)d_in[6];
    const float* ln2_b = (const float*)d_in[7];
    const float* w1    = (const float*)d_in[8];
    const float* b1    = (const float*)d_in[9];
    const float* w2    = (const float*)d_in[10];
    const float* b2    = (const float*)d_in[11];
    const float* w3    = (const float*)d_in[12];
    const float* b3    = (const float*)d_in[13];

    // ---- workspace layout (aliases temporally disjoint) ----
    char* ws = (char*)d_ws;
    unsigned short* wqkvT = (unsigned short*)(ws + 0);            // 6291456 B
    unsigned short* woutT = (unsigned short*)(ws + 6291456);      // 2097152 B
    unsigned short* w1T   = (unsigned short*)(ws + 8388608);      // 4194304 B
    unsigned short* w2T   = (unsigned short*)(ws + 12582912);     // 8388608 B
    unsigned short* w3T   = (unsigned short*)(ws + 20971520);     // 4194304 B
    unsigned short* Hbuf  = (unsigned short*)(ws + 25165824);     // 32 MB (ln1 out; later Abuf/H2)
    unsigned short* QKV   = (unsigned short*)(ws + 58720256);     // 96 MB (dead after attn_heads)
    float*          EP    = (float*)(ws + 159383552);             // 16 MB (attn phase)
    float*          CS    = (float*)(ws + 176160768);             // 256 KB
    float*          CTXF  = (float*)(ws + 176422912);             // 1 MB
    // phase 2 aliases:
    unsigned short* Abuf  = Hbuf;
    unsigned short* X2    = (unsigned short*)(ws + 58720256);     // x+attn bf16 [M,1024] (alias QKV head)
    unsigned short* H2    = Hbuf;
    unsigned short* Y1    = (unsigned short*)d_out;               // [M,2048] bf16 = out buffer
    unsigned short* Y2    = (unsigned short*)(ws + 125829120);    // 64 MB (alias QKV tail / EP region)

    transpose_cvt_all<<<12288, 256, 0, stream>>>(w_qkv, w_out, w1, w2, w3,
                                                 wqkvT, woutT, w1T, w2T, w3T);

    ln_kernel<0><<<MM, 256, 0, stream>>>(x, ln1_g, ln1_b, Hbuf, 1);

    gemm_bt<0><<<dim3(3072/128, MM/128), 256, 0, stream>>>(Hbuf, wqkvT, QKV, nullptr, nullptr, MM, 3072, 1024);

    ctx_partial<<<dim3(16, HH, BB), 256, 0, stream>>>(QKV, EP, CS);
    ctx_reduce<<<BB*HH, 256, 0, stream>>>(EP, CS, CTXF);
    attn_heads<<<dim3(256, HH), 256, 0, stream>>>(QKV, CTXF, Abuf);

    gemm_bt<2><<<dim3(1024/128, MM/128), 256, 0, stream>>>(Abuf, woutT, X2, b_out, x, MM, 1024, 1024);

    ln_kernel<1><<<MM, 256, 0, stream>>>(X2, ln2_g, ln2_b, H2, 0);

    gemm_bt<1><<<dim3(2048/128, MM/128), 256, 0, stream>>>(H2, w1T, Y1, b1, nullptr, MM, 2048, 1024);
    gemm_bt<1><<<dim3(2048/128, MM/128), 256, 0, stream>>>(Y1, w2T, Y2, b2, nullptr, MM, 2048, 2048);
    gemm_bt<3><<<dim3(1024/128, MM/128), 256, 0, stream>>>(Y2, w3T, d_out, b3, X2, MM, 1024, 2048);
}